// Round 2
// baseline (3269.394 us; speedup 1.0000x reference)
//
#include <hip/hip_runtime.h>

// Zero-phase FIR (reflect_limited) as direct correlation: out[t] = sum_k g[k]*e[t+k],
// g[k] = h[412-k].  R2: kill the LDS-pipe bottleneck (was ~1 ds_read per 4 FMAs).
//   - 16 outputs/thread, sliding window w[16] in registers (static rotation).
//   - e-tile in group-of-4 interleaved LDS layout -> one ds_read_b128 refills 4 slots,
//     lane stride 16B (8-phase conflict-free), compile-time offsets.
//   - filter read as broadcast float4 (1 LDS op / 4 taps).
// => ~2 LDS ops per 128 FMAs; fp32 VALU pipe becomes the binding resource (~215us floor).

#define T_LEN    10000
#define N_H      413
#define SHIFT    206         // (N_H-1)/2
#define TILE     4096        // 256 threads * 16 outputs
#define NTILES   3           // 4096+4096+1808
#define ROWSTRIDE 1128       // floats per interleave row = ceil(ceil(4508/4)/4)*4
#define LDS_E_FLOATS (4 * ROWSTRIDE)   // 4512

// One group of 4 taps, s = 4*u + P (P compile-time).  Window invariant entering:
// w[(4P+d)&15] = et[16u + 4P + d], d=0..15.  Refill et[...+16..19] lands in the 4
// slots vacated this group, each written right after its last use.
#define DO_GROUP(u, P) do {                                                        \
    const float4 g4 = gv[4 * (u) + (P)];                                           \
    const float4 nw = ev[(P) * 282 + t + (u) + 1];                                 \
    _Pragma("unroll") for (int r = 0; r < 16; ++r)                                 \
        acc[r] += g4.x * w[(4 * (P) + 0 + r) & 15];                                \
    w[(4 * (P) + 0) & 15] = nw.x;                                                  \
    _Pragma("unroll") for (int r = 0; r < 16; ++r)                                 \
        acc[r] += g4.y * w[(4 * (P) + 1 + r) & 15];                                \
    w[(4 * (P) + 1) & 15] = nw.y;                                                  \
    _Pragma("unroll") for (int r = 0; r < 16; ++r)                                 \
        acc[r] += g4.z * w[(4 * (P) + 2 + r) & 15];                                \
    w[(4 * (P) + 2) & 15] = nw.z;                                                  \
    _Pragma("unroll") for (int r = 0; r < 16; ++r)                                 \
        acc[r] += g4.w * w[(4 * (P) + 3 + r) & 15];                                \
    w[(4 * (P) + 3) & 15] = nw.w;                                                  \
} while (0)

__global__ __launch_bounds__(256, 8) void FilterBank_20624432955781_kernel(
    const float* __restrict__ x, const float* __restrict__ h, float* __restrict__ out) {
    __shared__ alignas(16) float lds_e[LDS_E_FLOATS];
    __shared__ alignas(16) float lds_g[416];

    const int t = threadIdx.x;
    const int tile_start = blockIdx.x * TILE;
    const int row = blockIdx.y;
    const int n_out = min(TILE, T_LEN - tile_start);   // 4096 or 1808 (both %16==0)
    const int n_e = n_out + 412;

    const float* __restrict__ xrow = x + (size_t)row * T_LEN;

    // Stage reflect-extended e-tile into the grouped-interleaved layout:
    // addr(i) = ((i>>2)&3)*ROWSTRIDE + (i>>4)*4 + (i&3).
    for (int idx = t; idx < n_e; idx += 256) {
        const int j = tile_start + idx;                // global e index, [0, 10412)
        float v;
        if (j < SHIFT)                 v = 2.0f * xrow[0]         - xrow[SHIFT - j];
        else if (j < T_LEN + SHIFT)    v = xrow[j - SHIFT];
        else                           v = 2.0f * xrow[T_LEN - 1] - xrow[2 * T_LEN + SHIFT - 2 - j];
        lds_e[((idx >> 2) & 3) * ROWSTRIDE + ((idx >> 4) << 2) + (idx & 3)] = v;
    }
    // Reversed filter g[k] = h[412-k], padded to 416.
    for (int k = t; k < 416; k += 256) lds_g[k] = (k < N_H) ? h[N_H - 1 - k] : 0.0f;
    __syncthreads();

    if (t * 16 >= n_out) return;   // last tile: waves 2,3 exit (no later barriers)

    const float4* __restrict__ ev = reinterpret_cast<const float4*>(lds_e);
    const float4* __restrict__ gv = reinterpret_cast<const float4*>(lds_g);

    float acc[16], w[16];
    #pragma unroll
    for (int r = 0; r < 16; ++r) acc[r] = 0.0f;

    // Initial window: w[4p+c] = et[4p+c] = e_tile[16t + 4p + c].
    #pragma unroll
    for (int p = 0; p < 4; ++p) {
        const float4 v = ev[p * 282 + t];
        w[4 * p + 0] = v.x; w[4 * p + 1] = v.y; w[4 * p + 2] = v.z; w[4 * p + 3] = v.w;
    }

    // Taps k = 0..411 in 103 groups of 4; net window-slot permutation per u-iter is
    // identity, so no loop-carried register shuffles.
    for (int u = 0; u < 25; ++u) {
        DO_GROUP(u, 0); DO_GROUP(u, 1); DO_GROUP(u, 2); DO_GROUP(u, 3);
    }
    DO_GROUP(25, 0); DO_GROUP(25, 1); DO_GROUP(25, 2);
    // Final tap k = 412 (= 16*25+12 -> slot base 12).
    {
        const float gk = lds_g[412];
        #pragma unroll
        for (int r = 0; r < 16; ++r) acc[r] += gk * w[(12 + r) & 15];
    }

    float4* o4 = reinterpret_cast<float4*>(out + (size_t)row * T_LEN + tile_start + t * 16);
    o4[0] = make_float4(acc[0],  acc[1],  acc[2],  acc[3]);
    o4[1] = make_float4(acc[4],  acc[5],  acc[6],  acc[7]);
    o4[2] = make_float4(acc[8],  acc[9],  acc[10], acc[11]);
    o4[3] = make_float4(acc[12], acc[13], acc[14], acc[15]);
}

extern "C" void kernel_launch(void* const* d_in, const int* in_sizes, int n_in,
                              void* d_out, int out_size, void* d_ws, size_t ws_size,
                              hipStream_t stream) {
    const float* x = (const float*)d_in[0];   // [64,64,10000] fp32
    const float* h = (const float*)d_in[1];   // [413] fp32
    float* out = (float*)d_out;               // [64,64,10000] fp32
    dim3 grid(NTILES, 64 * 64);
    FilterBank_20624432955781_kernel<<<grid, dim3(256), 0, stream>>>(x, h, out);
}

// Round 3
// 590.576 us; speedup vs baseline: 5.5359x; 5.5359x over previous
//
#include <hip/hip_runtime.h>

// Zero-phase FIR (reflect_limited) as direct correlation: out[t] = sum_k g[k]*e[t+k],
// g[k] = h[412-k].
// R3 = R2 design with the spill bug fixed: __launch_bounds__(256,8) capped the VGPR
// budget at 64, forcing acc[16]/w[16] into scratch (12.5 GB HBM traffic, 7.5x slower).
// (256,4) gives a 128-VGPR budget; the arrays live in registers.
//   - 16 outputs/thread, sliding window w[16] in registers (static rotation).
//   - e-tile in group-of-4 interleaved LDS layout -> one ds_read_b128 refills 4 slots,
//     lane stride 16B (conflict-free), compile-time offsets.
//   - filter read as broadcast float4 (1 LDS op / 4 taps).
// => ~2 LDS ops per 128 FMAs; fp32 VALU pipe is the binding resource (~215us floor).

#define T_LEN    10000
#define N_H      413
#define SHIFT    206         // (N_H-1)/2
#define TILE     4096        // 256 threads * 16 outputs
#define NTILES   3           // 4096+4096+1808
#define ROWSTRIDE 1128       // floats per interleave row = ceil(ceil(4508/4)/4)*4
#define LDS_E_FLOATS (4 * ROWSTRIDE)   // 4512

// One group of 4 taps, s = 4*u + P (P compile-time).  Window invariant entering:
// w[(4P+d)&15] = et[16u + 4P + d], d=0..15.  Refill et[...+16..19] lands in the 4
// slots vacated this group, each written right after its last use.
#define DO_GROUP(u, P) do {                                                        \
    const float4 g4 = gv[4 * (u) + (P)];                                           \
    const float4 nw = ev[(P) * 282 + t + (u) + 1];                                 \
    _Pragma("unroll") for (int r = 0; r < 16; ++r)                                 \
        acc[r] += g4.x * w[(4 * (P) + 0 + r) & 15];                                \
    w[(4 * (P) + 0) & 15] = nw.x;                                                  \
    _Pragma("unroll") for (int r = 0; r < 16; ++r)                                 \
        acc[r] += g4.y * w[(4 * (P) + 1 + r) & 15];                                \
    w[(4 * (P) + 1) & 15] = nw.y;                                                  \
    _Pragma("unroll") for (int r = 0; r < 16; ++r)                                 \
        acc[r] += g4.z * w[(4 * (P) + 2 + r) & 15];                                \
    w[(4 * (P) + 2) & 15] = nw.z;                                                  \
    _Pragma("unroll") for (int r = 0; r < 16; ++r)                                 \
        acc[r] += g4.w * w[(4 * (P) + 3 + r) & 15];                                \
    w[(4 * (P) + 3) & 15] = nw.w;                                                  \
} while (0)

__global__ __launch_bounds__(256, 4) void FilterBank_20624432955781_kernel(
    const float* __restrict__ x, const float* __restrict__ h, float* __restrict__ out) {
    __shared__ alignas(16) float lds_e[LDS_E_FLOATS];
    __shared__ alignas(16) float lds_g[416];

    const int t = threadIdx.x;
    const int tile_start = blockIdx.x * TILE;
    const int row = blockIdx.y;
    const int n_out = min(TILE, T_LEN - tile_start);   // 4096 or 1808 (both %16==0)
    const int n_e = n_out + 412;

    const float* __restrict__ xrow = x + (size_t)row * T_LEN;

    // Stage reflect-extended e-tile into the grouped-interleaved layout:
    // addr(i) = ((i>>2)&3)*ROWSTRIDE + (i>>4)*4 + (i&3).  Conflict-free stores.
    for (int idx = t; idx < n_e; idx += 256) {
        const int j = tile_start + idx;                // global e index, [0, 10412)
        float v;
        if (j < SHIFT)                 v = 2.0f * xrow[0]         - xrow[SHIFT - j];
        else if (j < T_LEN + SHIFT)    v = xrow[j - SHIFT];
        else                           v = 2.0f * xrow[T_LEN - 1] - xrow[2 * T_LEN + SHIFT - 2 - j];
        lds_e[((idx >> 2) & 3) * ROWSTRIDE + ((idx >> 4) << 2) + (idx & 3)] = v;
    }
    // Reversed filter g[k] = h[412-k], padded to 416.
    for (int k = t; k < 416; k += 256) lds_g[k] = (k < N_H) ? h[N_H - 1 - k] : 0.0f;
    __syncthreads();

    if (t * 16 >= n_out) return;   // last tile: waves 2,3 exit (no later barriers)

    const float4* __restrict__ ev = reinterpret_cast<const float4*>(lds_e);
    const float4* __restrict__ gv = reinterpret_cast<const float4*>(lds_g);

    float acc[16], w[16];
    #pragma unroll
    for (int r = 0; r < 16; ++r) acc[r] = 0.0f;

    // Initial window: w[4p+c] = et[4p+c] = e_tile[16t + 4p + c].
    #pragma unroll
    for (int p = 0; p < 4; ++p) {
        const float4 v = ev[p * 282 + t];
        w[4 * p + 0] = v.x; w[4 * p + 1] = v.y; w[4 * p + 2] = v.z; w[4 * p + 3] = v.w;
    }

    // Taps k = 0..411 in 103 groups of 4; net window-slot permutation per u-iter is
    // identity, so no loop-carried register shuffles.
    for (int u = 0; u < 25; ++u) {
        DO_GROUP(u, 0); DO_GROUP(u, 1); DO_GROUP(u, 2); DO_GROUP(u, 3);
    }
    DO_GROUP(25, 0); DO_GROUP(25, 1); DO_GROUP(25, 2);
    // Final tap k = 412 (= 16*25+12 -> slot base 12).
    {
        const float gk = lds_g[412];
        #pragma unroll
        for (int r = 0; r < 16; ++r) acc[r] += gk * w[(12 + r) & 15];
    }

    float4* o4 = reinterpret_cast<float4*>(out + (size_t)row * T_LEN + tile_start + t * 16);
    o4[0] = make_float4(acc[0],  acc[1],  acc[2],  acc[3]);
    o4[1] = make_float4(acc[4],  acc[5],  acc[6],  acc[7]);
    o4[2] = make_float4(acc[8],  acc[9],  acc[10], acc[11]);
    o4[3] = make_float4(acc[12], acc[13], acc[14], acc[15]);
}

extern "C" void kernel_launch(void* const* d_in, const int* in_sizes, int n_in,
                              void* d_out, int out_size, void* d_ws, size_t ws_size,
                              hipStream_t stream) {
    const float* x = (const float*)d_in[0];   // [64,64,10000] fp32
    const float* h = (const float*)d_in[1];   // [413] fp32
    float* out = (float*)d_out;               // [64,64,10000] fp32
    dim3 grid(NTILES, 64 * 64);
    FilterBank_20624432955781_kernel<<<grid, dim3(256), 0, stream>>>(x, h, out);
}